// Round 17
// baseline (248.396 us; speedup 1.0000x reference)
//
#include <hip/hip_runtime.h>
#include <hip/hip_bf16.h>
#include <stdint.h>

#define B_  32
#define T_  512
#define C_  1024
#define NH_ 16
#define DH_ 64

typedef __attribute__((ext_vector_type(8))) __bf16 bf16x8;
typedef __attribute__((ext_vector_type(4))) __bf16 bf16x4;
typedef __attribute__((ext_vector_type(4))) float  f32x4;

__device__ __forceinline__ void gload_lds16(const void* g, void* lds) {
  __builtin_amdgcn_global_load_lds(
      (const __attribute__((address_space(1))) void*)(uintptr_t)g,
      (__attribute__((address_space(3))) void*)(uint32_t)(uintptr_t)lds,
      16, 0, 0);
}

// ---------------- fused prep: casts + rope tables (one launch) ----------------
__global__ void prep_kernel(const float* __restrict__ x,
                            const float* __restrict__ Wq, const float* __restrict__ Wk,
                            const float* __restrict__ Wv, const float* __restrict__ Wo,
                            __bf16* __restrict__ xb, __bf16* __restrict__ wqkv,
                            __bf16* __restrict__ wob,
                            float* __restrict__ cosT, float* __restrict__ sinT) {
  int i = blockIdx.x * blockDim.x + threadIdx.x;
  if (i < 4194304) {
    f32x4 v = *(const f32x4*)(x + (size_t)i * 4);
    bf16x4 o;
    o[0] = (__bf16)v[0]; o[1] = (__bf16)v[1]; o[2] = (__bf16)v[2]; o[3] = (__bf16)v[3];
    *(bf16x4*)(xb + (size_t)i * 4) = o;
  } else if (i < 5242880) {
    int j = i - 4194304;
    int w = j >> 18, idx = j & 262143;
    const float* src = (w == 0) ? Wq : (w == 1) ? Wk : (w == 2) ? Wv : Wo;
    __bf16* dst = (w == 3) ? wob : wqkv + (size_t)w * 1048576;
    f32x4 v = *(const f32x4*)(src + (size_t)idx * 4);
    bf16x4 o;
    o[0] = (__bf16)v[0]; o[1] = (__bf16)v[1]; o[2] = (__bf16)v[2]; o[3] = (__bf16)v[3];
    *(bf16x4*)(dst + (size_t)idx * 4) = o;
  } else if (i < 5259264) {
    int j = i - 5242880;            // T_*32
    int t = j >> 5, f = j & 31;
    float inv = powf(10000.0f, -(float)(2 * f) / 64.0f);
    float fr = (float)t * inv;
    cosT[j] = cosf(fr);
    sinT[j] = sinf(fr);
  }
}

// ------------ 256x256 BK64 8-phase counted-vmcnt GEMM (r11, measured best) ---
template <int MODE>
__global__ __launch_bounds__(512, 2) void gemm8(
    const __bf16* __restrict__ A,
    const __bf16* __restrict__ W0, const __bf16* __restrict__ W1, const __bf16* __restrict__ W2,
    __bf16* __restrict__ q, __bf16* __restrict__ k, __bf16* __restrict__ vt,
    float* __restrict__ outp) {
  extern __shared__ __bf16 lds[];
  const int K = C_;
  const int NH8 = 64;   // (K/64) tiles * 4 halves
  int tid = threadIdx.x;
  int lane = tid & 63, wave = tid >> 6;
  int ql = lane & 15, g = lane >> 4;
  int wr = wave >> 2, wc = wave & 3;

  constexpr int BNH = (MODE == 0) ? 6 : 2;   // bn per XCD (r6 L2-aware map)
  int bid = blockIdx.x;
  int xcd = bid & 7, local = bid >> 3;
  int bm = (xcd >> 1) * 16 + local / BNH;
  int bn = (xcd & 1) * BNH + local % BNH;

  const __bf16* Ag = A + (size_t)bm * 256 * K;
  const __bf16* Wg;
  if (MODE == 0) {
    int mat = bn >> 2;
    const __bf16* Wsel = (mat == 0) ? W0 : (mat == 1) ? W1 : W2;
    Wg = Wsel + (size_t)(bn & 3) * 256 * K;
  } else {
    Wg = W0 + (size_t)bn * 256 * K;
  }

  int schunk = (tid & 3) ^ ((tid >> 3) & 3);
  size_t stg_base = (size_t)(tid >> 2) * K + schunk * 8;

  int xsw = (g ^ ((ql >> 1) & 3)) * 8;
  int aoffW[8], boffW[4];
#pragma unroll
  for (int m = 0; m < 8; m++) aoffW[m] = (wr * 128 + m * 16 + ql) * 32 + xsw;
#pragma unroll
  for (int n = 0; n < 4; n++) boffW[n] = (wc * 64 + n * 16 + ql) * 32 + xsw;

#define STAGE_H(h)                                                          \
  if ((h) < NH8) {                                                          \
    int tl_ = (h) >> 2, pt_ = (h) & 3;                                      \
    const __bf16* s_ = ((pt_ & 1) ? Wg : Ag) + stg_base +                   \
                       (size_t)tl_ * 64 + (pt_ >> 1) * 32;                  \
    __bf16* d_ = lds + (((tl_ & 1) * 4 + pt_) * 8192) + tid * 8;            \
    gload_lds16(s_, d_);                                                    \
    gload_lds16(s_ + (size_t)128 * K, d_ + 4096);                           \
  }

#define PH(TP, KK, MLO, RB, SH, VM)                                         \
  {                                                                         \
    const __bf16* abase_ = lds + (((TP) * 4 + ((KK) ? 2 : 0)) * 8192);      \
    _Pragma("unroll")                                                       \
    for (int mm = 0; mm < 4; mm++)                                          \
      a[mm] = *(const bf16x8*)(abase_ + aoffW[(MLO) + mm]);                 \
    if (RB) {                                                               \
      const __bf16* bbase_ = lds + (((TP) * 4 + ((KK) ? 3 : 1)) * 8192);    \
      _Pragma("unroll")                                                     \
      for (int n = 0; n < 4; n++)                                           \
        b[n] = *(const bf16x8*)(bbase_ + boffW[n]);                         \
    }                                                                       \
    STAGE_H(SH);                                                            \
    __builtin_amdgcn_s_barrier();                                           \
    asm volatile("s_waitcnt lgkmcnt(0)" ::: "memory");                      \
    __builtin_amdgcn_sched_barrier(0);                                      \
    __builtin_amdgcn_s_setprio(1);                                          \
    _Pragma("unroll")                                                       \
    for (int mm = 0; mm < 4; mm++)                                          \
      _Pragma("unroll")                                                     \
      for (int n = 0; n < 4; n++)                                           \
        acc[(MLO) + mm][n] = __builtin_amdgcn_mfma_f32_16x16x32_bf16(       \
            a[mm], b[n], acc[(MLO) + mm][n], 0, 0, 0);                      \
    __builtin_amdgcn_s_setprio(0);                                          \
    {                                                                       \
      int vm_ = (VM);                                                       \
      if (vm_ == 0)      { asm volatile("s_waitcnt vmcnt(0)" ::: "memory"); } \
      else if (vm_ > 0)  { asm volatile("s_waitcnt vmcnt(6)" ::: "memory"); } \
    }                                                                       \
    __builtin_amdgcn_s_barrier();                                           \
  }

  STAGE_H(0); STAGE_H(1); STAGE_H(2); STAGE_H(3);
  STAGE_H(4); STAGE_H(5); STAGE_H(6);
  asm volatile("s_waitcnt vmcnt(6)" ::: "memory");
  __builtin_amdgcn_s_barrier();
  __builtin_amdgcn_sched_barrier(0);

  f32x4 acc[8][4] = {};
  bf16x8 a[4], b[4];
  for (int i = 0; i < 8; ++i) {
    int hb = 8 * i;
    int vm4 = (i == 7) ? 0 : 6;
    int vm8 = (i == 7) ? -1 : 6;
    PH(0, 0, 0, 1, hb + 7,  -1)
    PH(0, 0, 4, 0, hb + 8,  -1)
    PH(0, 1, 0, 1, hb + 9,  -1)
    PH(0, 1, 4, 0, hb + 10, vm4)
    PH(1, 0, 0, 1, hb + 11, -1)
    PH(1, 0, 4, 0, hb + 12, -1)
    PH(1, 1, 0, 1, hb + 13, -1)
    PH(1, 1, 4, 0, hb + 14, vm8)
  }
#undef PH
#undef STAGE_H

  int r0 = bm * 256 + wr * 128;
  int c0 = bn * 256 + wc * 64;
  if (MODE == 0) {
    int mat = c0 >> 10;  // block-uniform
#pragma unroll
    for (int m = 0; m < 8; m++) {
      int row = r0 + m * 16 + g * 4;
      int bb = row >> 9, tt = row & 511;
#pragma unroll
      for (int n = 0; n < 4; n++) {
        int col = c0 + n * 16 + ql;
        int h = (col & 1023) >> 6, d = col & 63;
        if (mat == 2) {
          bf16x4 ov;
#pragma unroll
          for (int r = 0; r < 4; r++) ov[r] = (__bf16)acc[m][n][r];
          *(bf16x4*)(vt + ((size_t)(bb * NH_ + h) * DH_ + d) * T_ + tt) = ov;
        } else {
          __bf16* dst = (mat == 0 ? q : k) + ((size_t)(bb * NH_ + h) * T_ + tt) * DH_ + d;
#pragma unroll
          for (int r = 0; r < 4; r++) dst[r * DH_] = (__bf16)acc[m][n][r];
        }
      }
    }
  } else {
#pragma unroll
    for (int m = 0; m < 8; m++) {
      int row = r0 + m * 16 + g * 4;
#pragma unroll
      for (int r = 0; r < 4; r++)
#pragma unroll
        for (int n = 0; n < 4; n++)
          outp[(size_t)(row + r) * C_ + c0 + n * 16 + ql] = acc[m][n][r];
    }
  }
}

// ------- flash attention: KV halves in LDS, 2 blocks/CU, PAIRED kv-tiles -----
// r16 structure (verified); r17: tiles {kv0, kv0+32} share ONE online-softmax
// update (= 64-wide tile): QK both tiles -> 4-chain batched max (pair-combine
// is local fmax, no extra shfl) -> one rescale decision -> exp+sum (pair sums
// combined locally before 2 shfls) -> 2 PV batches. kf/vf transient per tile
// to keep peak VGPR < 128 at (512,4).
__global__ __launch_bounds__(512, 4) void attn_kernel(
    const __bf16* __restrict__ qg, const __bf16* __restrict__ kg,
    const __bf16* __restrict__ vg, __bf16* __restrict__ ao,
    const float* __restrict__ cosT, const float* __restrict__ sinT) {
  extern __shared__ char smem[];
  __bf16* Klds = (__bf16*)smem;              // [256][64], chunk-XOR swizzled
  __bf16* Vlds = (__bf16*)(smem + 32768);    // [64][260] padded

  int tid = threadIdx.x;
  int lane = tid & 63, wave = tid >> 6;      // wave 0..7
  int ql = lane & 15, g = lane >> 4;
  int bh = blockIdx.x & 511;
  int qhalf = blockIdx.x >> 9;
  int b = bh >> 4, h = bh & 15;
  const __bf16* qp = qg + (size_t)bh * (T_ * DH_);
  const __bf16* kp = kg + (size_t)bh * (T_ * DH_);
  const __bf16* vp = vg + (size_t)bh * (T_ * DH_);  // [DH][T]

  // ---- load + rope Q (scale 1/8): 32 rows/wave, 2 s-slots ----
  int q0 = qhalf * 256 + wave * 32;
  bf16x8 qf[2][2];
#pragma unroll
  for (int s = 0; s < 2; s++)
#pragma unroll
    for (int kk = 0; kk < 2; kk++) {
      int tq = q0 + s * 16 + ql;
      bf16x8 raw = *(const bf16x8*)(qp + (size_t)tq * DH_ + kk * 32 + g * 8);
      int fb = tq * 32 + kk * 16 + g * 4;
      f32x4 c4 = *(const f32x4*)(cosT + fb);
      f32x4 s4 = *(const f32x4*)(sinT + fb);
      bf16x8 out;
#pragma unroll
      for (int p = 0; p < 4; p++) {
        float a0 = (float)raw[2 * p], a1 = (float)raw[2 * p + 1];
        out[2 * p]     = (__bf16)(0.125f * (a0 * c4[p] - a1 * s4[p]));
        out[2 * p + 1] = (__bf16)(0.125f * (a0 * s4[p] + a1 * c4[p]));
      }
      qf[s][kk] = out;
    }

  f32x4 o[2][4] = {};
  float mrow[2] = {-1e30f, -1e30f};
  float lrow[2] = {0.f, 0.f};

  for (int kvh = 0; kvh < 2; kvh++) {
    int kvbase = kvh * 256;
    // ---- stage K-half (with rope): 512 threads x 4 rows ----
    {
      int cb = tid & 7;
      int rb = tid >> 3;
#pragma unroll
      for (int i = 0; i < 4; i++) {
        int row = rb + i * 64;              // 0..255 local
        int grow = kvbase + row;
        bf16x8 raw = *(const bf16x8*)(kp + (size_t)grow * DH_ + cb * 8);
        f32x4 c4 = *(const f32x4*)(cosT + grow * 32 + cb * 4);
        f32x4 s4 = *(const f32x4*)(sinT + grow * 32 + cb * 4);
        bf16x8 out;
#pragma unroll
        for (int p = 0; p < 4; p++) {
          float a0 = (float)raw[2 * p], a1 = (float)raw[2 * p + 1];
          out[2 * p]     = (__bf16)(a0 * c4[p] - a1 * s4[p]);
          out[2 * p + 1] = (__bf16)(a0 * s4[p] + a1 * c4[p]);
        }
        *(bf16x8*)(Klds + row * 64 + ((cb ^ (row & 7)) * 8)) = out;
      }
    }
    // ---- stage V^T-half (linear, padded rows) ----
    {
      int d = tid >> 3;
      int cb = tid & 7;
      const __bf16* vrow = vp + (size_t)d * T_ + kvbase;
#pragma unroll
      for (int i = 0; i < 4; i++) {
        int c8 = cb + i * 8;
        bf16x8 raw = *(const bf16x8*)(vrow + c8 * 8);
        *(bf16x8*)(Vlds + d * 260 + c8 * 8) = raw;
      }
    }
    __syncthreads();

    for (int kv0 = 0; kv0 < 256; kv0 += 64) {
      // ---- 1) QK^T for tile pair (kf transient per tile) ----
      f32x4 sa[2][2], sb[2][2];   // [tile][s]
#pragma unroll
      for (int tt = 0; tt < 2; tt++) {
        int base = kv0 + tt * 32;
        bf16x8 kf[2][2];
#pragma unroll
        for (int sub = 0; sub < 2; sub++)
#pragma unroll
          for (int kk = 0; kk < 2; kk++) {
            int t = base + sub * 16 + ql;
            int cc = kk * 4 + g;
            kf[sub][kk] = *(const bf16x8*)(Klds + t * 64 + ((cc ^ (t & 7)) * 8));
          }
        __builtin_amdgcn_s_setprio(1);
#pragma unroll
        for (int s = 0; s < 2; s++) {
          sa[tt][s] = (f32x4){0.f, 0.f, 0.f, 0.f};
          sb[tt][s] = (f32x4){0.f, 0.f, 0.f, 0.f};
#pragma unroll
          for (int kk = 0; kk < 2; kk++) {
            sa[tt][s] = __builtin_amdgcn_mfma_f32_16x16x32_bf16(kf[0][kk], qf[s][kk], sa[tt][s], 0, 0, 0);
            sb[tt][s] = __builtin_amdgcn_mfma_f32_16x16x32_bf16(kf[1][kk], qf[s][kk], sb[tt][s], 0, 0, 0);
          }
        }
        __builtin_amdgcn_s_setprio(0);
      }

      // ---- 2) batched max: 4 independent chains, pair-combined locally ----
      float tm[2][2];
#pragma unroll
      for (int tt = 0; tt < 2; tt++)
#pragma unroll
        for (int s = 0; s < 2; s++) {
          float t0 = fmaxf(fmaxf(sa[tt][s][0], sa[tt][s][1]), fmaxf(sa[tt][s][2], sa[tt][s][3]));
          float t1 = fmaxf(fmaxf(sb[tt][s][0], sb[tt][s][1]), fmaxf(sb[tt][s][2], sb[tt][s][3]));
          tm[tt][s] = fmaxf(t0, t1);
        }
      float tmc[2];
#pragma unroll
      for (int s = 0; s < 2; s++) tmc[s] = fmaxf(tm[0][s], tm[1][s]);
#pragma unroll
      for (int s = 0; s < 2; s++) tmc[s] = fmaxf(tmc[s], __shfl_xor(tmc[s], 16));
#pragma unroll
      for (int s = 0; s < 2; s++) tmc[s] = fmaxf(tmc[s], __shfl_xor(tmc[s], 32));

      // ---- 3) one deferred-rescale decision per 64-row pair (THR=8) ----
      bool need = (tmc[0] > mrow[0] + 8.f) | (tmc[1] > mrow[1] + 8.f);
      if (__any(need)) {
#pragma unroll
        for (int s = 0; s < 2; s++) {
          float mnew = fmaxf(mrow[s], tmc[s]);
          float corr = __expf(mrow[s] - mnew);
          mrow[s] = mnew;
          lrow[s] *= corr;
#pragma unroll
          for (int c = 0; c < 4; c++) o[s][c] *= corr;
        }
      }

      // ---- 4) exp in place + pair-combined row sums ----
      float ps[2] = {0.f, 0.f};
#pragma unroll
      for (int tt = 0; tt < 2; tt++)
#pragma unroll
        for (int s = 0; s < 2; s++) {
#pragma unroll
          for (int r = 0; r < 4; r++) {
            sa[tt][s][r] = __expf(sa[tt][s][r] - mrow[s]);
            sb[tt][s][r] = __expf(sb[tt][s][r] - mrow[s]);
          }
          ps[s] += ((sa[tt][s][0] + sa[tt][s][1]) + (sa[tt][s][2] + sa[tt][s][3])) +
                   ((sb[tt][s][0] + sb[tt][s][1]) + (sb[tt][s][2] + sb[tt][s][3]));
        }
#pragma unroll
      for (int s = 0; s < 2; s++) ps[s] += __shfl_xor(ps[s], 16);
#pragma unroll
      for (int s = 0; s < 2; s++) { ps[s] += __shfl_xor(ps[s], 32); lrow[s] += ps[s]; }

      // ---- 5) P->bf16 + PV per tile (vf transient per tile) ----
#pragma unroll
      for (int tt = 0; tt < 2; tt++) {
        int base = kv0 + tt * 32;
        bf16x8 vf[4];
#pragma unroll
        for (int c = 0; c < 4; c++) {
          int d = c * 16 + ql;
          bf16x4 vlo = *(const bf16x4*)(Vlds + d * 260 + base + g * 4);
          bf16x4 vhi = *(const bf16x4*)(Vlds + d * 260 + base + 16 + g * 4);
#pragma unroll
          for (int r = 0; r < 4; r++) { vf[c][r] = vlo[r]; vf[c][4 + r] = vhi[r]; }
        }
        bf16x8 pb[2];
#pragma unroll
        for (int s = 0; s < 2; s++)
#pragma unroll
          for (int r = 0; r < 4; r++) {
            pb[s][r]     = (__bf16)sa[tt][s][r];
            pb[s][4 + r] = (__bf16)sb[tt][s][r];
          }
        __builtin_amdgcn_s_setprio(1);
#pragma unroll
        for (int s = 0; s < 2; s++)
#pragma unroll
          for (int c = 0; c < 4; c++)
            o[s][c] = __builtin_amdgcn_mfma_f32_16x16x32_bf16(vf[c], pb[s], o[s][c], 0, 0, 0);
        __builtin_amdgcn_s_setprio(0);
      }
    }
    __syncthreads();   // all waves done reading before next half overwrites
  }

#pragma unroll
  for (int s = 0; s < 2; s++) {
    float inv = 1.0f / lrow[s];
    size_t row = (size_t)b * T_ + q0 + s * 16 + ql;
    size_t baseo = row * C_ + h * DH_;
#pragma unroll
    for (int c = 0; c < 4; c++) {
      bf16x4 ov;
#pragma unroll
      for (int r = 0; r < 4; r++) ov[r] = (__bf16)(o[s][c][r] * inv);
      *(bf16x4*)(ao + baseo + c * 16 + g * 4) = ov;
    }
  }
}

extern "C" void kernel_launch(void* const* d_in, const int* in_sizes, int n_in,
                              void* d_out, int out_size, void* d_ws, size_t ws_size,
                              hipStream_t stream) {
  (void)in_sizes; (void)n_in; (void)out_size; (void)ws_size;
  const float* x  = (const float*)d_in[0];
  const float* Wq = (const float*)d_in[1];
  const float* Wk = (const float*)d_in[2];
  const float* Wv = (const float*)d_in[3];
  const float* Wo = (const float*)d_in[4];

  char* ws = (char*)d_ws;
  char* od = (char*)d_out;
  float* outp = (float*)d_out;

  // d_out hosts qb+kb (raw, un-roped; 32 MiB each); dead before out-proj overwrites.
  __bf16* qb = (__bf16*)(od);
  __bf16* kb = (__bf16*)(od + 33554432);
  // ws: xb/aob @0 (32M), vtb @32M (32M), wqkv @64M (6M), wob @70M (2M), tables @72M
  __bf16* xb   = (__bf16*)(ws);
  __bf16* vtb  = (__bf16*)(ws + 33554432);
  __bf16* wqkv = (__bf16*)(ws + 67108864);
  __bf16* wob  = (__bf16*)(ws + 73400320);
  float*  cosT = (float*)(ws + 75497472);
  float*  sinT = (float*)(ws + 75563008);
  __bf16* aob  = xb;  // x dead after QKV GEMM

  auto k0 = gemm8<0>; auto k1 = gemm8<1>;
  hipFuncSetAttribute((const void*)k0, hipFuncAttributeMaxDynamicSharedMemorySize, 131072);
  hipFuncSetAttribute((const void*)k1, hipFuncAttributeMaxDynamicSharedMemorySize, 131072);
  hipFuncSetAttribute((const void*)attn_kernel, hipFuncAttributeMaxDynamicSharedMemorySize, 66560);

  // 1) fused casts + rope tables
  prep_kernel<<<dim3(20544), dim3(256), 0, stream>>>(
      x, Wq, Wk, Wv, Wo, xb, wqkv, wob, cosT, sinT);

  // 2) QKV: M=16384, N=3072 -> 768 blocks (8-phase BK64)
  gemm8<0><<<dim3(768), dim3(512), 131072, stream>>>(
      xb, wqkv, wqkv + 1048576, wqkv + 2097152, qb, kb, vtb, nullptr);

  // 3) attention (KV-halved LDS, 2 blocks/CU, paired kv-tiles)
  attn_kernel<<<dim3(1024), dim3(512), 66560, stream>>>(
      qb, kb, vtb, aob, cosT, sinT);

  // 4) out-proj: M=16384, N=1024 -> 256 blocks (8-phase BK64)
  gemm8<1><<<dim3(256), dim3(512), 131072, stream>>>(
      aob, wob, nullptr, nullptr, nullptr, nullptr, nullptr, outp);
}

// Round 18
// 241.808 us; speedup vs baseline: 1.0272x; 1.0272x over previous
//
#include <hip/hip_runtime.h>
#include <hip/hip_bf16.h>
#include <stdint.h>

#define B_  32
#define T_  512
#define C_  1024
#define NH_ 16
#define DH_ 64

typedef __attribute__((ext_vector_type(8))) __bf16 bf16x8;
typedef __attribute__((ext_vector_type(4))) __bf16 bf16x4;
typedef __attribute__((ext_vector_type(4))) float  f32x4;

__device__ __forceinline__ void gload_lds16(const void* g, void* lds) {
  __builtin_amdgcn_global_load_lds(
      (const __attribute__((address_space(1))) void*)(uintptr_t)g,
      (__attribute__((address_space(3))) void*)(uint32_t)(uintptr_t)lds,
      16, 0, 0);
}

// ---------------- fused prep: casts + rope tables (one launch) ----------------
__global__ void prep_kernel(const float* __restrict__ x,
                            const float* __restrict__ Wq, const float* __restrict__ Wk,
                            const float* __restrict__ Wv, const float* __restrict__ Wo,
                            __bf16* __restrict__ xb, __bf16* __restrict__ wqkv,
                            __bf16* __restrict__ wob,
                            float* __restrict__ cosT, float* __restrict__ sinT) {
  int i = blockIdx.x * blockDim.x + threadIdx.x;
  if (i < 4194304) {
    f32x4 v = *(const f32x4*)(x + (size_t)i * 4);
    bf16x4 o;
    o[0] = (__bf16)v[0]; o[1] = (__bf16)v[1]; o[2] = (__bf16)v[2]; o[3] = (__bf16)v[3];
    *(bf16x4*)(xb + (size_t)i * 4) = o;
  } else if (i < 5242880) {
    int j = i - 4194304;
    int w = j >> 18, idx = j & 262143;
    const float* src = (w == 0) ? Wq : (w == 1) ? Wk : (w == 2) ? Wv : Wo;
    __bf16* dst = (w == 3) ? wob : wqkv + (size_t)w * 1048576;
    f32x4 v = *(const f32x4*)(src + (size_t)idx * 4);
    bf16x4 o;
    o[0] = (__bf16)v[0]; o[1] = (__bf16)v[1]; o[2] = (__bf16)v[2]; o[3] = (__bf16)v[3];
    *(bf16x4*)(dst + (size_t)idx * 4) = o;
  } else if (i < 5259264) {
    int j = i - 5242880;            // T_*32
    int t = j >> 5, f = j & 31;
    float inv = powf(10000.0f, -(float)(2 * f) / 64.0f);
    float fr = (float)t * inv;
    cosT[j] = cosf(fr);
    sinT[j] = sinf(fr);
  }
}

// ------------ 256x256 BK64 8-phase counted-vmcnt GEMM (r11, measured best) ---
template <int MODE>
__global__ __launch_bounds__(512, 2) void gemm8(
    const __bf16* __restrict__ A,
    const __bf16* __restrict__ W0, const __bf16* __restrict__ W1, const __bf16* __restrict__ W2,
    __bf16* __restrict__ q, __bf16* __restrict__ k, __bf16* __restrict__ vt,
    float* __restrict__ outp) {
  extern __shared__ __bf16 lds[];
  const int K = C_;
  const int NH8 = 64;   // (K/64) tiles * 4 halves
  int tid = threadIdx.x;
  int lane = tid & 63, wave = tid >> 6;
  int ql = lane & 15, g = lane >> 4;
  int wr = wave >> 2, wc = wave & 3;

  constexpr int BNH = (MODE == 0) ? 6 : 2;   // bn per XCD (r6 L2-aware map)
  int bid = blockIdx.x;
  int xcd = bid & 7, local = bid >> 3;
  int bm = (xcd >> 1) * 16 + local / BNH;
  int bn = (xcd & 1) * BNH + local % BNH;

  const __bf16* Ag = A + (size_t)bm * 256 * K;
  const __bf16* Wg;
  if (MODE == 0) {
    int mat = bn >> 2;
    const __bf16* Wsel = (mat == 0) ? W0 : (mat == 1) ? W1 : W2;
    Wg = Wsel + (size_t)(bn & 3) * 256 * K;
  } else {
    Wg = W0 + (size_t)bn * 256 * K;
  }

  int schunk = (tid & 3) ^ ((tid >> 3) & 3);
  size_t stg_base = (size_t)(tid >> 2) * K + schunk * 8;

  int xsw = (g ^ ((ql >> 1) & 3)) * 8;
  int aoffW[8], boffW[4];
#pragma unroll
  for (int m = 0; m < 8; m++) aoffW[m] = (wr * 128 + m * 16 + ql) * 32 + xsw;
#pragma unroll
  for (int n = 0; n < 4; n++) boffW[n] = (wc * 64 + n * 16 + ql) * 32 + xsw;

#define STAGE_H(h)                                                          \
  if ((h) < NH8) {                                                          \
    int tl_ = (h) >> 2, pt_ = (h) & 3;                                      \
    const __bf16* s_ = ((pt_ & 1) ? Wg : Ag) + stg_base +                   \
                       (size_t)tl_ * 64 + (pt_ >> 1) * 32;                  \
    __bf16* d_ = lds + (((tl_ & 1) * 4 + pt_) * 8192) + tid * 8;            \
    gload_lds16(s_, d_);                                                    \
    gload_lds16(s_ + (size_t)128 * K, d_ + 4096);                           \
  }

#define PH(TP, KK, MLO, RB, SH, VM)                                         \
  {                                                                         \
    const __bf16* abase_ = lds + (((TP) * 4 + ((KK) ? 2 : 0)) * 8192);      \
    _Pragma("unroll")                                                       \
    for (int mm = 0; mm < 4; mm++)                                          \
      a[mm] = *(const bf16x8*)(abase_ + aoffW[(MLO) + mm]);                 \
    if (RB) {                                                               \
      const __bf16* bbase_ = lds + (((TP) * 4 + ((KK) ? 3 : 1)) * 8192);    \
      _Pragma("unroll")                                                     \
      for (int n = 0; n < 4; n++)                                           \
        b[n] = *(const bf16x8*)(bbase_ + boffW[n]);                         \
    }                                                                       \
    STAGE_H(SH);                                                            \
    __builtin_amdgcn_s_barrier();                                           \
    asm volatile("s_waitcnt lgkmcnt(0)" ::: "memory");                      \
    __builtin_amdgcn_sched_barrier(0);                                      \
    __builtin_amdgcn_s_setprio(1);                                          \
    _Pragma("unroll")                                                       \
    for (int mm = 0; mm < 4; mm++)                                          \
      _Pragma("unroll")                                                     \
      for (int n = 0; n < 4; n++)                                           \
        acc[(MLO) + mm][n] = __builtin_amdgcn_mfma_f32_16x16x32_bf16(       \
            a[mm], b[n], acc[(MLO) + mm][n], 0, 0, 0);                      \
    __builtin_amdgcn_s_setprio(0);                                          \
    {                                                                       \
      int vm_ = (VM);                                                       \
      if (vm_ == 0)      { asm volatile("s_waitcnt vmcnt(0)" ::: "memory"); } \
      else if (vm_ > 0)  { asm volatile("s_waitcnt vmcnt(6)" ::: "memory"); } \
    }                                                                       \
    __builtin_amdgcn_s_barrier();                                           \
  }

  STAGE_H(0); STAGE_H(1); STAGE_H(2); STAGE_H(3);
  STAGE_H(4); STAGE_H(5); STAGE_H(6);
  asm volatile("s_waitcnt vmcnt(6)" ::: "memory");
  __builtin_amdgcn_s_barrier();
  __builtin_amdgcn_sched_barrier(0);

  f32x4 acc[8][4] = {};
  bf16x8 a[4], b[4];
  for (int i = 0; i < 8; ++i) {
    int hb = 8 * i;
    int vm4 = (i == 7) ? 0 : 6;
    int vm8 = (i == 7) ? -1 : 6;
    PH(0, 0, 0, 1, hb + 7,  -1)
    PH(0, 0, 4, 0, hb + 8,  -1)
    PH(0, 1, 0, 1, hb + 9,  -1)
    PH(0, 1, 4, 0, hb + 10, vm4)
    PH(1, 0, 0, 1, hb + 11, -1)
    PH(1, 0, 4, 0, hb + 12, -1)
    PH(1, 1, 0, 1, hb + 13, -1)
    PH(1, 1, 4, 0, hb + 14, vm8)
  }
#undef PH
#undef STAGE_H

  int r0 = bm * 256 + wr * 128;
  int c0 = bn * 256 + wc * 64;
  if (MODE == 0) {
    int mat = c0 >> 10;  // block-uniform
#pragma unroll
    for (int m = 0; m < 8; m++) {
      int row = r0 + m * 16 + g * 4;
      int bb = row >> 9, tt = row & 511;
#pragma unroll
      for (int n = 0; n < 4; n++) {
        int col = c0 + n * 16 + ql;
        int h = (col & 1023) >> 6, d = col & 63;
        if (mat == 2) {
          bf16x4 ov;
#pragma unroll
          for (int r = 0; r < 4; r++) ov[r] = (__bf16)acc[m][n][r];
          *(bf16x4*)(vt + ((size_t)(bb * NH_ + h) * DH_ + d) * T_ + tt) = ov;
        } else {
          __bf16* dst = (mat == 0 ? q : k) + ((size_t)(bb * NH_ + h) * T_ + tt) * DH_ + d;
#pragma unroll
          for (int r = 0; r < 4; r++) dst[r * DH_] = (__bf16)acc[m][n][r];
        }
      }
    }
  } else {
#pragma unroll
    for (int m = 0; m < 8; m++) {
      int row = r0 + m * 16 + g * 4;
#pragma unroll
      for (int r = 0; r < 4; r++)
#pragma unroll
        for (int n = 0; n < 4; n++)
          outp[(size_t)(row + r) * C_ + c0 + n * 16 + ql] = acc[m][n][r];
    }
  }
}

// ---------------- flash attention: 1024-thread block (16 waves, 4/SIMD) -----
// Best measured attn (r14, 62us). LDS-resident K (rope fused at staging,
// XOR-swizzled [512][64]) + V^T (padded [64][516]); 16 waves x 32 q-rows;
// batched inner loop (one QK MFMA region, 2-chain vectorized softmax, one
// __any-gated defer-max rescale, one PV region).
__global__ __launch_bounds__(1024) void attn_kernel(
    const __bf16* __restrict__ qg, const __bf16* __restrict__ kg,
    const __bf16* __restrict__ vg, __bf16* __restrict__ ao,
    const float* __restrict__ cosT, const float* __restrict__ sinT) {
  extern __shared__ char smem[];
  __bf16* Klds = (__bf16*)smem;              // [512][64], chunk-XOR swizzled
  __bf16* Vlds = (__bf16*)(smem + 65536);    // [64][516] padded

  int tid = threadIdx.x;
  int lane = tid & 63, wave = tid >> 6;      // wave 0..15
  int ql = lane & 15, g = lane >> 4;
  int bh = blockIdx.x;
  int b = bh >> 4, h = bh & 15;
  const __bf16* qp = qg + (size_t)bh * (T_ * DH_);
  const __bf16* kp = kg + (size_t)bh * (T_ * DH_);
  const __bf16* vp = vg + (size_t)bh * (T_ * DH_);  // [DH][T]

  // ---- stage K (with rope): 1024 threads x 4 rows ----
  {
    int cb = tid & 7;       // 16B chunk within row
    int rb = tid >> 3;      // row base 0..127
#pragma unroll
    for (int i = 0; i < 4; i++) {
      int row = rb + i * 128;
      bf16x8 raw = *(const bf16x8*)(kp + (size_t)row * DH_ + cb * 8);
      f32x4 c4 = *(const f32x4*)(cosT + row * 32 + cb * 4);
      f32x4 s4 = *(const f32x4*)(sinT + row * 32 + cb * 4);
      bf16x8 out;
#pragma unroll
      for (int p = 0; p < 4; p++) {
        float a0 = (float)raw[2 * p], a1 = (float)raw[2 * p + 1];
        out[2 * p]     = (__bf16)(a0 * c4[p] - a1 * s4[p]);
        out[2 * p + 1] = (__bf16)(a0 * s4[p] + a1 * c4[p]);
      }
      *(bf16x8*)(Klds + row * 64 + ((cb ^ (row & 7)) * 8)) = out;
    }
  }
  // ---- stage V^T (linear, padded rows): 1024 threads x 4 chunks ----
  {
    int d = tid >> 4;          // 0..63
    int cb = tid & 15;
    const __bf16* vrow = vp + (size_t)d * T_;
#pragma unroll
    for (int i = 0; i < 4; i++) {
      int c8 = cb + i * 16;    // 16B chunk 0..63 within row
      bf16x8 raw = *(const bf16x8*)(vrow + c8 * 8);
      *(bf16x8*)(Vlds + d * 516 + c8 * 8) = raw;
    }
  }

  // ---- load + rope Q (scale 1/8): 2 s-slots per wave ----
  int q0 = wave * 32;
  bf16x8 qf[2][2];
#pragma unroll
  for (int s = 0; s < 2; s++)
#pragma unroll
    for (int kk = 0; kk < 2; kk++) {
      int tq = q0 + s * 16 + ql;
      bf16x8 raw = *(const bf16x8*)(qp + (size_t)tq * DH_ + kk * 32 + g * 8);
      int fb = tq * 32 + kk * 16 + g * 4;
      f32x4 c4 = *(const f32x4*)(cosT + fb);
      f32x4 s4 = *(const f32x4*)(sinT + fb);
      bf16x8 out;
#pragma unroll
      for (int p = 0; p < 4; p++) {
        float a0 = (float)raw[2 * p], a1 = (float)raw[2 * p + 1];
        out[2 * p]     = (__bf16)(0.125f * (a0 * c4[p] - a1 * s4[p]));
        out[2 * p + 1] = (__bf16)(0.125f * (a0 * s4[p] + a1 * c4[p]));
      }
      qf[s][kk] = out;
    }

  __syncthreads();

  f32x4 o[2][4] = {};
  float mrow[2] = {-1e30f, -1e30f};
  float lrow[2] = {0.f, 0.f};

  for (int kv0 = 0; kv0 < T_; kv0 += 32) {
    // K fragments for this tile
    bf16x8 kf[2][2];
#pragma unroll
    for (int sub = 0; sub < 2; sub++)
#pragma unroll
      for (int kk = 0; kk < 2; kk++) {
        int t = kv0 + sub * 16 + ql;
        int cc = kk * 4 + g;
        kf[sub][kk] = *(const bf16x8*)(Klds + t * 64 + ((cc ^ (t & 7)) * 8));
      }

    // ---- 1) QK^T for both s (one MFMA region) ----
    f32x4 sa[2], sb[2];
    __builtin_amdgcn_s_setprio(1);
#pragma unroll
    for (int s = 0; s < 2; s++) {
      sa[s] = (f32x4){0.f, 0.f, 0.f, 0.f};
      sb[s] = (f32x4){0.f, 0.f, 0.f, 0.f};
#pragma unroll
      for (int kk = 0; kk < 2; kk++) {
        sa[s] = __builtin_amdgcn_mfma_f32_16x16x32_bf16(kf[0][kk], qf[s][kk], sa[s], 0, 0, 0);
        sb[s] = __builtin_amdgcn_mfma_f32_16x16x32_bf16(kf[1][kk], qf[s][kk], sb[s], 0, 0, 0);
      }
    }
    __builtin_amdgcn_s_setprio(0);

    // V fragments (after QK: kf dead, vf live -> lower peak regs)
    bf16x8 vf[4];
#pragma unroll
    for (int c = 0; c < 4; c++) {
      int d = c * 16 + ql;
      bf16x4 vlo = *(const bf16x4*)(Vlds + d * 516 + kv0 + g * 4);
      bf16x4 vhi = *(const bf16x4*)(Vlds + d * 516 + kv0 + 16 + g * 4);
#pragma unroll
      for (int r = 0; r < 4; r++) { vf[c][r] = vlo[r]; vf[c][4 + r] = vhi[r]; }
    }

    // ---- 2) tile max per s ----
    float tm[2];
#pragma unroll
    for (int s = 0; s < 2; s++) {
      float t0 = fmaxf(fmaxf(sa[s][0], sa[s][1]), fmaxf(sa[s][2], sa[s][3]));
      float t1 = fmaxf(fmaxf(sb[s][0], sb[s][1]), fmaxf(sb[s][2], sb[s][3]));
      tm[s] = fmaxf(t0, t1);
    }
#pragma unroll
    for (int s = 0; s < 2; s++) tm[s] = fmaxf(tm[s], __shfl_xor(tm[s], 16));
#pragma unroll
    for (int s = 0; s < 2; s++) tm[s] = fmaxf(tm[s], __shfl_xor(tm[s], 32));

    // ---- 3) single deferred-rescale branch (THR=8, exact math) ----
    bool need = (tm[0] > mrow[0] + 8.f) | (tm[1] > mrow[1] + 8.f);
    if (__any(need)) {
#pragma unroll
      for (int s = 0; s < 2; s++) {
        float mnew = fmaxf(mrow[s], tm[s]);
        float corr = __expf(mrow[s] - mnew);
        mrow[s] = mnew;
        lrow[s] *= corr;
#pragma unroll
        for (int c = 0; c < 4; c++) o[s][c] *= corr;
      }
    }

    // ---- 4) exp in place + row sums ----
    float ps[2];
#pragma unroll
    for (int s = 0; s < 2; s++) {
#pragma unroll
      for (int r = 0; r < 4; r++) {
        sa[s][r] = __expf(sa[s][r] - mrow[s]);
        sb[s][r] = __expf(sb[s][r] - mrow[s]);
      }
      ps[s] = ((sa[s][0] + sa[s][1]) + (sa[s][2] + sa[s][3])) +
              ((sb[s][0] + sb[s][1]) + (sb[s][2] + sb[s][3]));
    }
#pragma unroll
    for (int s = 0; s < 2; s++) ps[s] += __shfl_xor(ps[s], 16);
#pragma unroll
    for (int s = 0; s < 2; s++) { ps[s] += __shfl_xor(ps[s], 32); lrow[s] += ps[s]; }

    // ---- 5) P->bf16 + PV MFMAs (one region) ----
    bf16x8 pb[2];
#pragma unroll
    for (int s = 0; s < 2; s++)
#pragma unroll
      for (int r = 0; r < 4; r++) {
        pb[s][r]     = (__bf16)sa[s][r];
        pb[s][4 + r] = (__bf16)sb[s][r];
      }
    __builtin_amdgcn_s_setprio(1);
#pragma unroll
    for (int s = 0; s < 2; s++)
#pragma unroll
      for (int c = 0; c < 4; c++)
        o[s][c] = __builtin_amdgcn_mfma_f32_16x16x32_bf16(vf[c], pb[s], o[s][c], 0, 0, 0);
    __builtin_amdgcn_s_setprio(0);
  }

#pragma unroll
  for (int s = 0; s < 2; s++) {
    float inv = 1.0f / lrow[s];
    size_t row = (size_t)b * T_ + q0 + s * 16 + ql;
    size_t baseo = row * C_ + h * DH_;
#pragma unroll
    for (int c = 0; c < 4; c++) {
      bf16x4 ov;
#pragma unroll
      for (int r = 0; r < 4; r++) ov[r] = (__bf16)(o[s][c][r] * inv);
      *(bf16x4*)(ao + baseo + c * 16 + g * 4) = ov;
    }
  }
}

extern "C" void kernel_launch(void* const* d_in, const int* in_sizes, int n_in,
                              void* d_out, int out_size, void* d_ws, size_t ws_size,
                              hipStream_t stream) {
  (void)in_sizes; (void)n_in; (void)out_size; (void)ws_size;
  const float* x  = (const float*)d_in[0];
  const float* Wq = (const float*)d_in[1];
  const float* Wk = (const float*)d_in[2];
  const float* Wv = (const float*)d_in[3];
  const float* Wo = (const float*)d_in[4];

  char* ws = (char*)d_ws;
  char* od = (char*)d_out;
  float* outp = (float*)d_out;

  // d_out hosts qb+kb (raw, un-roped; 32 MiB each); dead before out-proj overwrites.
  __bf16* qb = (__bf16*)(od);
  __bf16* kb = (__bf16*)(od + 33554432);
  // ws: xb/aob @0 (32M), vtb @32M (32M), wqkv @64M (6M), wob @70M (2M), tables @72M
  __bf16* xb   = (__bf16*)(ws);
  __bf16* vtb  = (__bf16*)(ws + 33554432);
  __bf16* wqkv = (__bf16*)(ws + 67108864);
  __bf16* wob  = (__bf16*)(ws + 73400320);
  float*  cosT = (float*)(ws + 75497472);
  float*  sinT = (float*)(ws + 75563008);
  __bf16* aob  = xb;  // x dead after QKV GEMM

  auto k0 = gemm8<0>; auto k1 = gemm8<1>;
  hipFuncSetAttribute((const void*)k0, hipFuncAttributeMaxDynamicSharedMemorySize, 131072);
  hipFuncSetAttribute((const void*)k1, hipFuncAttributeMaxDynamicSharedMemorySize, 131072);
  hipFuncSetAttribute((const void*)attn_kernel, hipFuncAttributeMaxDynamicSharedMemorySize, 131584);

  // 1) fused casts + rope tables
  prep_kernel<<<dim3(20544), dim3(256), 0, stream>>>(
      x, Wq, Wk, Wv, Wo, xb, wqkv, wob, cosT, sinT);

  // 2) QKV: M=16384, N=3072 -> 768 blocks (8-phase BK64)
  gemm8<0><<<dim3(768), dim3(512), 131072, stream>>>(
      xb, wqkv, wqkv + 1048576, wqkv + 2097152, qb, kb, vtb, nullptr);

  // 3) attention (LDS-resident K/V, fused rope, 1024-thread blocks)
  attn_kernel<<<dim3(B_ * NH_), dim3(1024), 131584, stream>>>(
      qb, kb, vtb, aob, cosT, sinT);

  // 4) out-proj: M=16384, N=1024 -> 256 blocks (8-phase BK64)
  gemm8<1><<<dim3(256), dim3(512), 131072, stream>>>(
      aob, wob, nullptr, nullptr, nullptr, nullptr, nullptr, outp);
}